// Round 17
// baseline (492.290 us; speedup 1.0000x reference)
//
#include <hip/hip_runtime.h>
#include <hip/hip_bf16.h>
#include <hip/hip_fp16.h>

// GAT: N=50000 nodes, DIN=128, HID=128 (4 heads x 32), DOUT=16, E=800000 (+N self loops)
// CSR: fixed-capacity 64 ushort slots/node (deg <= 64 guaranteed by construction).
// Aggregation (layers 1-3): head-quarter-sliced — wave (node, q) gathers ONLY the 64B
// line of head q from each source row; quarter = blockIdx&3 maps quarter q to XCDs
// {q, q+4} under blockIdx%8 round-robin, making the 3.2MB slice L2-resident per XCD.

typedef _Float16 half8_t __attribute__((ext_vector_type(8)));
typedef float f32x4_t  __attribute__((ext_vector_type(4)));

static inline int divup(int a, int b){ return (a + b - 1) / b; }

// ---------------- zero cnt ----------------

__global__ __launch_bounds__(256) void zero_cnt_kernel(int* __restrict__ cnt, int n){
    int i = blockIdx.x * 256 + threadIdx.x;     // int4 granularity
    int4 z = {0, 0, 0, 0};
    if (i * 4 + 3 < n){
        *(int4*)(cnt + i * 4) = z;
    } else {
        for (int j = i * 4; j < n; ++j) cnt[j] = 0;
    }
}

// ---------------- CSR build: one pass, dst-sliced ----------------

__global__ __launch_bounds__(256) void fill_sliced_kernel(const int* __restrict__ src,
                                                          const int* __restrict__ dst,
                                                          int* __restrict__ cnt,
                                                          unsigned short* __restrict__ csr,
                                                          int E, int Et){
    int slice = blockIdx.x & 7;
    int e = (blockIdx.x >> 3) * 256 + threadIdx.x;
    if (e >= Et) return;
    int d = (e < E) ? dst[e] : (e - E);          // self loop for e >= E
    if (((d >> 4) & 7) != slice) return;         // 16-node runs per slice
    int s = (e < E) ? src[e] : d;
    int pos = atomicAdd(&cnt[d], 1);
    csr[(d << 6) + pos] = (unsigned short)s;
}

// ---------------- prep: WTx[l][144][128] + W2x[32][128] (fp16) ----------------

__global__ __launch_bounds__(256) void prep_kernel(const float* __restrict__ W1,
                                                   const float* __restrict__ Wh,
                                                   const float* __restrict__ as1,
                                                   const float* __restrict__ ad1,
                                                   const float* __restrict__ ash,
                                                   const float* __restrict__ adh,
                                                   const float* __restrict__ W2,
                                                   const float* __restrict__ as2,
                                                   const float* __restrict__ ad2,
                                                   _Float16* __restrict__ WTx,
                                                   _Float16* __restrict__ W2x){
    int id = blockIdx.x * 256 + threadIdx.x;     // 3*144*128 + 32*128
    const int MAIN = 3 * 144 * 128;
    if (id < MAIN){
        int l = id / (144 * 128), rem = id % (144 * 128);
        int c = rem >> 7, k = rem & 127;
        const float* W = (l == 0) ? W1 : (Wh + (size_t)(l - 1) * 16384);
        float v = 0.f;
        if (c < 128){
            v = W[k * 128 + c];
        } else if (c < 136){
            int h = (c - 128) & 3;
            const float* a = (c < 132) ? ((l == 0) ? as1 : ash + (size_t)(l - 1) * 128)
                                       : ((l == 0) ? ad1 : adh + (size_t)(l - 1) * 128);
            const float* wr = W + k * 128 + h * 32;
            const float* ar = a + h * 32;
            float sum = 0.f;
            #pragma unroll
            for (int c2 = 0; c2 < 32; ++c2) sum += wr[c2] * ar[c2];
            v = sum;
        }
        WTx[id] = (_Float16)v;
    } else if (id < MAIN + 32 * 128){
        int id2 = id - MAIN;
        int c = id2 >> 7, k = id2 & 127;
        float v = 0.f;
        if (c < 16){
            v = W2[k * 16 + c];
        } else if (c == 16 || c == 17){
            const float* a = (c == 16) ? as2 : ad2;
            float sum = 0.f;
            #pragma unroll
            for (int j = 0; j < 16; ++j) sum += W2[k * 16 + j] * a[j];
            v = sum;
        }
        W2x[id2] = (_Float16)v;
    }
}

// ---------------- fused GEMM+logits via MFMA (layers 1-3) ----------------

template<bool F32IN>
__device__ __forceinline__ void gemm128L_body(const void* __restrict__ Xv,
                                              const _Float16* __restrict__ WTx,
                                              _Float16* __restrict__ H16,
                                              float* __restrict__ als,
                                              float* __restrict__ ald, int n){
    int wav = threadIdx.x >> 6, lane = threadIdx.x & 63;
    int nb = blockIdx.x * 16;
    int r = lane & 15, kg = lane >> 4;
    int anode = nb + r; if (anode >= n) anode = n - 1;

    half8_t a0, a1, a2, a3;
    if (F32IN){
        const float* xrow = (const float*)Xv + (size_t)anode * 128 + kg * 8;
        #pragma unroll
        for (int q = 0; q < 4; ++q){
            float4 u = *(const float4*)(xrow + q * 32);
            float4 w = *(const float4*)(xrow + q * 32 + 4);
            half8_t o = {(_Float16)u.x,(_Float16)u.y,(_Float16)u.z,(_Float16)u.w,
                         (_Float16)w.x,(_Float16)w.y,(_Float16)w.z,(_Float16)w.w};
            if (q == 0) a0 = o; else if (q == 1) a1 = o; else if (q == 2) a2 = o; else a3 = o;
        }
    } else {
        const _Float16* xrow = (const _Float16*)Xv + (size_t)anode * 128 + kg * 8;
        a0 = *(const half8_t*)(xrow);
        a1 = *(const half8_t*)(xrow + 32);
        a2 = *(const half8_t*)(xrow + 64);
        a3 = *(const half8_t*)(xrow + 96);
    }

    const _Float16* wc0 = WTx + (size_t)(wav * 32 + r) * 128 + kg * 8;
    const _Float16* wc1 = wc0 + 16 * 128;

    f32x4_t c0 = {0.f,0.f,0.f,0.f}, c1 = {0.f,0.f,0.f,0.f};
    c0 = __builtin_amdgcn_mfma_f32_16x16x32_f16(a0, *(const half8_t*)(wc0     ), c0, 0,0,0);
    c1 = __builtin_amdgcn_mfma_f32_16x16x32_f16(a0, *(const half8_t*)(wc1     ), c1, 0,0,0);
    c0 = __builtin_amdgcn_mfma_f32_16x16x32_f16(a1, *(const half8_t*)(wc0 + 32), c0, 0,0,0);
    c1 = __builtin_amdgcn_mfma_f32_16x16x32_f16(a1, *(const half8_t*)(wc1 + 32), c1, 0,0,0);
    c0 = __builtin_amdgcn_mfma_f32_16x16x32_f16(a2, *(const half8_t*)(wc0 + 64), c0, 0,0,0);
    c1 = __builtin_amdgcn_mfma_f32_16x16x32_f16(a2, *(const half8_t*)(wc1 + 64), c1, 0,0,0);
    c0 = __builtin_amdgcn_mfma_f32_16x16x32_f16(a3, *(const half8_t*)(wc0 + 96), c0, 0,0,0);
    c1 = __builtin_amdgcn_mfma_f32_16x16x32_f16(a3, *(const half8_t*)(wc1 + 96), c1, 0,0,0);

    int colw = wav * 32 + r;
    #pragma unroll
    for (int rg = 0; rg < 4; ++rg){
        int onode = nb + kg * 4 + rg;
        if (onode < n){
            _Float16* hr = H16 + (size_t)onode * 128 + colw;
            hr[0]  = (_Float16)c0[rg];
            hr[16] = (_Float16)c1[rg];
        }
    }

    if (wav == 0){
        const _Float16* wl = WTx + (size_t)(128 + r) * 128 + kg * 8;
        f32x4_t cl = {0.f,0.f,0.f,0.f};
        cl = __builtin_amdgcn_mfma_f32_16x16x32_f16(a0, *(const half8_t*)(wl     ), cl, 0,0,0);
        cl = __builtin_amdgcn_mfma_f32_16x16x32_f16(a1, *(const half8_t*)(wl + 32), cl, 0,0,0);
        cl = __builtin_amdgcn_mfma_f32_16x16x32_f16(a2, *(const half8_t*)(wl + 64), cl, 0,0,0);
        cl = __builtin_amdgcn_mfma_f32_16x16x32_f16(a3, *(const half8_t*)(wl + 96), cl, 0,0,0);
        if (r < 8){
            #pragma unroll
            for (int rg = 0; rg < 4; ++rg){
                int onode = nb + kg * 4 + rg;
                if (onode < n){
                    if (r < 4) als[(size_t)onode * 4 + r]       = cl[rg];
                    else       ald[(size_t)onode * 4 + (r - 4)] = cl[rg];
                }
            }
        }
    }
}

__global__ __launch_bounds__(256) void gemm128L_f32_kernel(const float* __restrict__ X,
                                                           const _Float16* __restrict__ WTx,
                                                           _Float16* __restrict__ H16,
                                                           float* __restrict__ als,
                                                           float* __restrict__ ald, int n){
    gemm128L_body<true>(X, WTx, H16, als, ald, n);
}

__global__ __launch_bounds__(256) void gemm128L_f16_kernel(const _Float16* __restrict__ X16,
                                                           const _Float16* __restrict__ WTx,
                                                           _Float16* __restrict__ H16,
                                                           float* __restrict__ als,
                                                           float* __restrict__ ald, int n){
    gemm128L_body<false>(X16, WTx, H16, als, ald, n);
}

// ---------------- layer-4 GEMM+logits via MFMA: H4(fp16) + als4/ald4 ----------------

__global__ __launch_bounds__(256) void gemm16L_kernel(const _Float16* __restrict__ X16,
                                                      const _Float16* __restrict__ W2x,
                                                      _Float16* __restrict__ H4,
                                                      float* __restrict__ als4,
                                                      float* __restrict__ ald4, int n){
    int wav = threadIdx.x >> 6, lane = threadIdx.x & 63;
    int nb = blockIdx.x * 64 + wav * 16;
    int r = lane & 15, kg = lane >> 4;
    int anode = nb + r; if (anode >= n) anode = n - 1;

    const _Float16* xrow = X16 + (size_t)anode * 128 + kg * 8;
    half8_t a0 = *(const half8_t*)(xrow);
    half8_t a1 = *(const half8_t*)(xrow + 32);
    half8_t a2 = *(const half8_t*)(xrow + 64);
    half8_t a3 = *(const half8_t*)(xrow + 96);

    const _Float16* wc0 = W2x + (size_t)r * 128 + kg * 8;
    const _Float16* wc1 = wc0 + 16 * 128;

    f32x4_t c0 = {0.f,0.f,0.f,0.f}, c1 = {0.f,0.f,0.f,0.f};
    c0 = __builtin_amdgcn_mfma_f32_16x16x32_f16(a0, *(const half8_t*)(wc0     ), c0, 0,0,0);
    c1 = __builtin_amdgcn_mfma_f32_16x16x32_f16(a0, *(const half8_t*)(wc1     ), c1, 0,0,0);
    c0 = __builtin_amdgcn_mfma_f32_16x16x32_f16(a1, *(const half8_t*)(wc0 + 32), c0, 0,0,0);
    c1 = __builtin_amdgcn_mfma_f32_16x16x32_f16(a1, *(const half8_t*)(wc1 + 32), c1, 0,0,0);
    c0 = __builtin_amdgcn_mfma_f32_16x16x32_f16(a2, *(const half8_t*)(wc0 + 64), c0, 0,0,0);
    c1 = __builtin_amdgcn_mfma_f32_16x16x32_f16(a2, *(const half8_t*)(wc1 + 64), c1, 0,0,0);
    c0 = __builtin_amdgcn_mfma_f32_16x16x32_f16(a3, *(const half8_t*)(wc0 + 96), c0, 0,0,0);
    c1 = __builtin_amdgcn_mfma_f32_16x16x32_f16(a3, *(const half8_t*)(wc1 + 96), c1, 0,0,0);

    #pragma unroll
    for (int rg = 0; rg < 4; ++rg){
        int onode = nb + kg * 4 + rg;
        if (onode < n){
            H4[(size_t)onode * 16 + r] = (_Float16)c0[rg];
            if (r == 0) als4[onode] = c1[rg];       // col 16
            else if (r == 1) ald4[onode] = c1[rg];  // col 17
        }
    }
}

// ---------------- aggregation (layers 1-3): head-quarter-sliced, L2-resident gather ----------------
// block = 4 waves, all quarter q = blockIdx&3; wave handles node (blockIdx>>2)*4+wid.
// Wave gathers ONLY bytes [64q,64q+64) of each source row: 4 edge-groups x 16 ch-lanes
// (2 fp16/lane). Weights: head q only (1 exp/edge). csr via nontemporal (no reuse here).

__global__ __launch_bounds__(256) void aggregate128q_kernel(const _Float16* __restrict__ H16,
                                                            const float* __restrict__ als,
                                                            const float* __restrict__ ald,
                                                            const int* __restrict__ cnt,
                                                            const unsigned short* __restrict__ csr,
                                                            const float* __restrict__ bias,
                                                            _Float16* __restrict__ out16,
                                                            int n){
    int q = blockIdx.x & 3;                      // quarter == head
    int node = (blockIdx.x >> 2) * 4 + (threadIdx.x >> 6);
    int lane = threadIdx.x & 63;
    if (node >= n) return;
    int start = node << 6;
    int deg = cnt[node];
    int end = start + deg;

    int eg = lane >> 4, cl = lane & 15;          // 4 edge-groups x 16 ch-lanes
    float ad_h = ald[(size_t)node * 4 + q];

    float den = 0.f, accx = 0.f, accy = 0.f;
    const _Float16* Hq = H16 + q * 32 + cl * 2;
    int i = start + eg;
    for (; i + 4 < end; i += 8){
        int sA = __builtin_nontemporal_load(&csr[i]);
        int sB = __builtin_nontemporal_load(&csr[i + 4]);
        float eA = als[(size_t)sA * 4 + q] + ad_h; eA = eA > 0.f ? eA : 0.2f * eA;
        float eB = als[(size_t)sB * 4 + q] + ad_h; eB = eB > 0.f ? eB : 0.2f * eB;
        float wA = __expf(eA);
        float wB = __expf(eB);
        den += wA + wB;
        unsigned int ua = *(const unsigned int*)(Hq + (size_t)sA * 128);
        unsigned int ub = *(const unsigned int*)(Hq + (size_t)sB * 128);
        float2 fa = __half22float2(*(__half2*)&ua);
        float2 fb = __half22float2(*(__half2*)&ub);
        accx += wA * fa.x + wB * fb.x;
        accy += wA * fa.y + wB * fb.y;
    }
    if (i < end){
        int s = __builtin_nontemporal_load(&csr[i]);
        float e = als[(size_t)s * 4 + q] + ad_h; e = e > 0.f ? e : 0.2f * e;
        float w = __expf(e);
        den += w;
        unsigned int ua = *(const unsigned int*)(Hq + (size_t)s * 128);
        float2 fa = __half22float2(*(__half2*)&ua);
        accx += w * fa.x; accy += w * fa.y;
    }
    // reduce over the 4 edge-groups (full-exec reconvergence point)
    accx += __shfl_xor(accx, 16); accx += __shfl_xor(accx, 32);
    accy += __shfl_xor(accy, 16); accy += __shfl_xor(accy, 32);
    den  += __shfl_xor(den, 16);  den  += __shfl_xor(den, 32);

    if (eg == 0){
        float inv = 1.f / (den + 1e-16f);
        int col = q * 32 + cl * 2;
        float vx = accx * inv + bias[col];
        float vy = accy * inv + bias[col + 1];
        vx = vx > 0.f ? vx : __expf(vx) - 1.f;   // ELU
        vy = vy > 0.f ? vy : __expf(vy) - 1.f;
        __half2 o = __floats2half2_rn(vx, vy);
        __builtin_nontemporal_store(*(unsigned int*)&o,
                                    (unsigned int*)(out16 + (size_t)node * 128 + col));
    }
}

// ---------------- aggregation (16 ch, 1 head): fp16 gather, in-loop form ----------------

__global__ __launch_bounds__(256) void aggregate16_kernel(const _Float16* __restrict__ H4,
                                                          const float* __restrict__ als4,
                                                          const float* __restrict__ ald4,
                                                          const int* __restrict__ cnt,
                                                          const unsigned short* __restrict__ csr,
                                                          const float* __restrict__ bias,
                                                          float* __restrict__ out, int n){
    int node = blockIdx.x * 4 + (threadIdx.x >> 6);
    int lane = threadIdx.x & 63;
    if (node >= n) return;
    int start = node << 6, deg = cnt[node];
    float adn = ald4[node];

    int eg = lane >> 2, cl = lane & 3;
    float den = 0.f;
    float acc0 = 0.f, acc1 = 0.f, acc2 = 0.f, acc3 = 0.f;
    for (int i = eg; i < deg; i += 16){
        int s = csr[start + i];
        float e = als4[s] + adn; e = e > 0.f ? e : 0.2f * e;
        float w = __expf(e);
        den += w;
        uint2 hv = *(const uint2*)(H4 + (size_t)s * 16 + cl * 4);
        float2 h0 = __half22float2(*(__half2*)&hv.x);
        float2 h1 = __half22float2(*(__half2*)&hv.y);
        acc0 += w * h0.x; acc1 += w * h0.y; acc2 += w * h1.x; acc3 += w * h1.y;
    }
    #pragma unroll
    for (int off = 4; off <= 32; off <<= 1){
        acc0 += __shfl_xor(acc0, off); acc1 += __shfl_xor(acc1, off);
        acc2 += __shfl_xor(acc2, off); acc3 += __shfl_xor(acc3, off);
        den  += __shfl_xor(den,  off);
    }

    if (eg == 0){
        float inv = 1.f / (den + 1e-16f);
        float4 bv = *(const float4*)(bias + cl * 4);
        float4 o = {acc0*inv + bv.x, acc1*inv + bv.y, acc2*inv + bv.z, acc3*inv + bv.w};
        *(float4*)&out[(size_t)node * 16 + cl * 4] = o;
    }
}

// ---------------- launcher ----------------

extern "C" void kernel_launch(void* const* d_in, const int* in_sizes, int n_in,
                              void* d_out, int out_size, void* d_ws, size_t ws_size,
                              hipStream_t stream) {
    const float* x   = (const float*)d_in[0];
    const int*   ei  = (const int*)d_in[1];
    const float* W1  = (const float*)d_in[3];
    const float* as1 = (const float*)d_in[4];
    const float* ad1 = (const float*)d_in[5];
    const float* b1  = (const float*)d_in[6];
    const float* Wh  = (const float*)d_in[7];
    const float* ash = (const float*)d_in[8];
    const float* adh = (const float*)d_in[9];
    const float* bh  = (const float*)d_in[10];
    const float* W2  = (const float*)d_in[11];
    const float* as2 = (const float*)d_in[12];
    const float* ad2 = (const float*)d_in[13];
    const float* b2  = (const float*)d_in[14];

    int N = in_sizes[0] / 128;
    int E = in_sizes[1] / 2;
    int Et = E + N;
    const int* srcA = ei;
    const int* dstA = ei + E;

    char* ws = (char*)d_ws;
    size_t off = 0;
    auto alloc = [&](size_t bytes) -> void* {
        void* p = ws + off;
        off = (off + bytes + 255) & ~(size_t)255;
        return p;
    };
    int* cnt      = (int*)alloc((size_t)N * 4);
    unsigned short* csr = (unsigned short*)alloc((size_t)N * 64 * 2);
    _Float16* xbuf16 = (_Float16*)alloc((size_t)N * 128 * 2);
    _Float16* h16    = (_Float16*)alloc((size_t)N * 128 * 2);
    _Float16* wtx    = (_Float16*)alloc((size_t)3 * 144 * 128 * 2);
    _Float16* w2x    = (_Float16*)alloc((size_t)32 * 128 * 2);
    float* als_a  = (float*)alloc((size_t)N * 4 * 4);
    float* ald_a  = (float*)alloc((size_t)N * 4 * 4);
    _Float16* h4  = (_Float16*)alloc((size_t)N * 16 * 2);
    float* als4   = (float*)alloc((size_t)N * 4);
    float* ald4   = (float*)alloc((size_t)N * 4);

    zero_cnt_kernel<<<divup(divup(N, 4), 256), 256, 0, stream>>>(cnt, N);
    prep_kernel<<<divup(3 * 144 * 128 + 32 * 128, 256), 256, 0, stream>>>(
        W1, Wh, as1, ad1, ash, adh, W2, as2, ad2, wtx, w2x);
    fill_sliced_kernel<<<divup(Et, 256) * 8, 256, 0, stream>>>(srcA, dstA, cnt, csr, E, Et);

    float* out = (float*)d_out;
    const size_t WSTRIDE = (size_t)144 * 128;
    int aggq_grid = divup(N, 4) * 4;            // (node-group, quarter) blocks

    // layer 1 (fp32 input, converted in-register)
    gemm128L_f32_kernel<<<divup(N, 16), 256, 0, stream>>>(x, wtx, h16, als_a, ald_a, N);
    aggregate128q_kernel<<<aggq_grid, 256, 0, stream>>>(h16, als_a, ald_a, cnt, csr,
                                                        b1, xbuf16, N);
    // layer 2
    gemm128L_f16_kernel<<<divup(N, 16), 256, 0, stream>>>(xbuf16, wtx + WSTRIDE, h16, als_a, ald_a, N);
    aggregate128q_kernel<<<aggq_grid, 256, 0, stream>>>(h16, als_a, ald_a, cnt, csr,
                                                        bh, xbuf16, N);
    // layer 3
    gemm128L_f16_kernel<<<divup(N, 16), 256, 0, stream>>>(xbuf16, wtx + 2 * WSTRIDE, h16, als_a, ald_a, N);
    aggregate128q_kernel<<<aggq_grid, 256, 0, stream>>>(h16, als_a, ald_a, cnt, csr,
                                                        bh + 128, xbuf16, N);

    // layer 4 (heads=1, 16 out): fused GEMM+logits, fp16 H4
    gemm16L_kernel<<<divup(N, 64), 256, 0, stream>>>(xbuf16, w2x, h4, als4, ald4, N);
    aggregate16_kernel<<<divup(N, 4), 256, 0, stream>>>(h4, als4, ald4, cnt, csr, b2, out, N);
}

// Round 18
// 258.593 us; speedup vs baseline: 1.9037x; 1.9037x over previous
//
#include <hip/hip_runtime.h>
#include <hip/hip_bf16.h>
#include <hip/hip_fp16.h>

// GAT: N=50000 nodes, DIN=128, HID=128 (4 heads x 32), DOUT=16, E=800000 (+N self loops)
// CSR: fixed-capacity 64 ushort slots/node (deg <= 64 guaranteed by construction).
// Aggregation: round-12 in-loop unroll-x2 form — empirical optimum. Survived four
// attack attempts: r14 LDS-hoist (-3%), r15 unroll-x4 (-5%), r17 head-quarter-slice
// (-90%, FETCH rose 95->143MB: XCD mapping assumption false + 4x metadata re-read).
// Kernel is L2/fabric random-gather bound: 218MB logical -> 95MB FETCH @ ~56% L2 hit.

typedef _Float16 half8_t __attribute__((ext_vector_type(8)));
typedef float f32x4_t  __attribute__((ext_vector_type(4)));

static inline int divup(int a, int b){ return (a + b - 1) / b; }

// ---------------- zero cnt ----------------

__global__ __launch_bounds__(256) void zero_cnt_kernel(int* __restrict__ cnt, int n){
    int i = blockIdx.x * 256 + threadIdx.x;     // int4 granularity
    int4 z = {0, 0, 0, 0};
    if (i * 4 + 3 < n){
        *(int4*)(cnt + i * 4) = z;
    } else {
        for (int j = i * 4; j < n; ++j) cnt[j] = 0;
    }
}

// ---------------- CSR build: one pass, dst-sliced ----------------

__global__ __launch_bounds__(256) void fill_sliced_kernel(const int* __restrict__ src,
                                                          const int* __restrict__ dst,
                                                          int* __restrict__ cnt,
                                                          unsigned short* __restrict__ csr,
                                                          int E, int Et){
    int slice = blockIdx.x & 7;
    int e = (blockIdx.x >> 3) * 256 + threadIdx.x;
    if (e >= Et) return;
    int d = (e < E) ? dst[e] : (e - E);          // self loop for e >= E
    if (((d >> 4) & 7) != slice) return;         // 16-node runs per slice
    int s = (e < E) ? src[e] : d;
    int pos = atomicAdd(&cnt[d], 1);
    csr[(d << 6) + pos] = (unsigned short)s;
}

// ---------------- prep: WTx[l][144][128] + W2x[32][128] (fp16) ----------------

__global__ __launch_bounds__(256) void prep_kernel(const float* __restrict__ W1,
                                                   const float* __restrict__ Wh,
                                                   const float* __restrict__ as1,
                                                   const float* __restrict__ ad1,
                                                   const float* __restrict__ ash,
                                                   const float* __restrict__ adh,
                                                   const float* __restrict__ W2,
                                                   const float* __restrict__ as2,
                                                   const float* __restrict__ ad2,
                                                   _Float16* __restrict__ WTx,
                                                   _Float16* __restrict__ W2x){
    int id = blockIdx.x * 256 + threadIdx.x;     // 3*144*128 + 32*128
    const int MAIN = 3 * 144 * 128;
    if (id < MAIN){
        int l = id / (144 * 128), rem = id % (144 * 128);
        int c = rem >> 7, k = rem & 127;
        const float* W = (l == 0) ? W1 : (Wh + (size_t)(l - 1) * 16384);
        float v = 0.f;
        if (c < 128){
            v = W[k * 128 + c];
        } else if (c < 136){
            int h = (c - 128) & 3;
            const float* a = (c < 132) ? ((l == 0) ? as1 : ash + (size_t)(l - 1) * 128)
                                       : ((l == 0) ? ad1 : adh + (size_t)(l - 1) * 128);
            const float* wr = W + k * 128 + h * 32;
            const float* ar = a + h * 32;
            float sum = 0.f;
            #pragma unroll
            for (int c2 = 0; c2 < 32; ++c2) sum += wr[c2] * ar[c2];
            v = sum;
        }
        WTx[id] = (_Float16)v;
    } else if (id < MAIN + 32 * 128){
        int id2 = id - MAIN;
        int c = id2 >> 7, k = id2 & 127;
        float v = 0.f;
        if (c < 16){
            v = W2[k * 16 + c];
        } else if (c == 16 || c == 17){
            const float* a = (c == 16) ? as2 : ad2;
            float sum = 0.f;
            #pragma unroll
            for (int j = 0; j < 16; ++j) sum += W2[k * 16 + j] * a[j];
            v = sum;
        }
        W2x[id2] = (_Float16)v;
    }
}

// ---------------- fused GEMM+logits via MFMA (layers 1-3) ----------------

template<bool F32IN>
__device__ __forceinline__ void gemm128L_body(const void* __restrict__ Xv,
                                              const _Float16* __restrict__ WTx,
                                              _Float16* __restrict__ H16,
                                              float* __restrict__ als,
                                              float* __restrict__ ald, int n){
    int wav = threadIdx.x >> 6, lane = threadIdx.x & 63;
    int nb = blockIdx.x * 16;
    int r = lane & 15, kg = lane >> 4;
    int anode = nb + r; if (anode >= n) anode = n - 1;

    half8_t a0, a1, a2, a3;
    if (F32IN){
        const float* xrow = (const float*)Xv + (size_t)anode * 128 + kg * 8;
        #pragma unroll
        for (int q = 0; q < 4; ++q){
            float4 u = *(const float4*)(xrow + q * 32);
            float4 w = *(const float4*)(xrow + q * 32 + 4);
            half8_t o = {(_Float16)u.x,(_Float16)u.y,(_Float16)u.z,(_Float16)u.w,
                         (_Float16)w.x,(_Float16)w.y,(_Float16)w.z,(_Float16)w.w};
            if (q == 0) a0 = o; else if (q == 1) a1 = o; else if (q == 2) a2 = o; else a3 = o;
        }
    } else {
        const _Float16* xrow = (const _Float16*)Xv + (size_t)anode * 128 + kg * 8;
        a0 = *(const half8_t*)(xrow);
        a1 = *(const half8_t*)(xrow + 32);
        a2 = *(const half8_t*)(xrow + 64);
        a3 = *(const half8_t*)(xrow + 96);
    }

    const _Float16* wc0 = WTx + (size_t)(wav * 32 + r) * 128 + kg * 8;
    const _Float16* wc1 = wc0 + 16 * 128;

    f32x4_t c0 = {0.f,0.f,0.f,0.f}, c1 = {0.f,0.f,0.f,0.f};
    c0 = __builtin_amdgcn_mfma_f32_16x16x32_f16(a0, *(const half8_t*)(wc0     ), c0, 0,0,0);
    c1 = __builtin_amdgcn_mfma_f32_16x16x32_f16(a0, *(const half8_t*)(wc1     ), c1, 0,0,0);
    c0 = __builtin_amdgcn_mfma_f32_16x16x32_f16(a1, *(const half8_t*)(wc0 + 32), c0, 0,0,0);
    c1 = __builtin_amdgcn_mfma_f32_16x16x32_f16(a1, *(const half8_t*)(wc1 + 32), c1, 0,0,0);
    c0 = __builtin_amdgcn_mfma_f32_16x16x32_f16(a2, *(const half8_t*)(wc0 + 64), c0, 0,0,0);
    c1 = __builtin_amdgcn_mfma_f32_16x16x32_f16(a2, *(const half8_t*)(wc1 + 64), c1, 0,0,0);
    c0 = __builtin_amdgcn_mfma_f32_16x16x32_f16(a3, *(const half8_t*)(wc0 + 96), c0, 0,0,0);
    c1 = __builtin_amdgcn_mfma_f32_16x16x32_f16(a3, *(const half8_t*)(wc1 + 96), c1, 0,0,0);

    int colw = wav * 32 + r;
    #pragma unroll
    for (int rg = 0; rg < 4; ++rg){
        int onode = nb + kg * 4 + rg;
        if (onode < n){
            _Float16* hr = H16 + (size_t)onode * 128 + colw;
            hr[0]  = (_Float16)c0[rg];
            hr[16] = (_Float16)c1[rg];
        }
    }

    if (wav == 0){
        const _Float16* wl = WTx + (size_t)(128 + r) * 128 + kg * 8;
        f32x4_t cl = {0.f,0.f,0.f,0.f};
        cl = __builtin_amdgcn_mfma_f32_16x16x32_f16(a0, *(const half8_t*)(wl     ), cl, 0,0,0);
        cl = __builtin_amdgcn_mfma_f32_16x16x32_f16(a1, *(const half8_t*)(wl + 32), cl, 0,0,0);
        cl = __builtin_amdgcn_mfma_f32_16x16x32_f16(a2, *(const half8_t*)(wl + 64), cl, 0,0,0);
        cl = __builtin_amdgcn_mfma_f32_16x16x32_f16(a3, *(const half8_t*)(wl + 96), cl, 0,0,0);
        if (r < 8){
            #pragma unroll
            for (int rg = 0; rg < 4; ++rg){
                int onode = nb + kg * 4 + rg;
                if (onode < n){
                    if (r < 4) als[(size_t)onode * 4 + r]       = cl[rg];
                    else       ald[(size_t)onode * 4 + (r - 4)] = cl[rg];
                }
            }
        }
    }
}

__global__ __launch_bounds__(256) void gemm128L_f32_kernel(const float* __restrict__ X,
                                                           const _Float16* __restrict__ WTx,
                                                           _Float16* __restrict__ H16,
                                                           float* __restrict__ als,
                                                           float* __restrict__ ald, int n){
    gemm128L_body<true>(X, WTx, H16, als, ald, n);
}

__global__ __launch_bounds__(256) void gemm128L_f16_kernel(const _Float16* __restrict__ X16,
                                                           const _Float16* __restrict__ WTx,
                                                           _Float16* __restrict__ H16,
                                                           float* __restrict__ als,
                                                           float* __restrict__ ald, int n){
    gemm128L_body<false>(X16, WTx, H16, als, ald, n);
}

// ---------------- layer-4 GEMM+logits via MFMA: H4(fp16) + als4/ald4 ----------------

__global__ __launch_bounds__(256) void gemm16L_kernel(const _Float16* __restrict__ X16,
                                                      const _Float16* __restrict__ W2x,
                                                      _Float16* __restrict__ H4,
                                                      float* __restrict__ als4,
                                                      float* __restrict__ ald4, int n){
    int wav = threadIdx.x >> 6, lane = threadIdx.x & 63;
    int nb = blockIdx.x * 64 + wav * 16;
    int r = lane & 15, kg = lane >> 4;
    int anode = nb + r; if (anode >= n) anode = n - 1;

    const _Float16* xrow = X16 + (size_t)anode * 128 + kg * 8;
    half8_t a0 = *(const half8_t*)(xrow);
    half8_t a1 = *(const half8_t*)(xrow + 32);
    half8_t a2 = *(const half8_t*)(xrow + 64);
    half8_t a3 = *(const half8_t*)(xrow + 96);

    const _Float16* wc0 = W2x + (size_t)r * 128 + kg * 8;
    const _Float16* wc1 = wc0 + 16 * 128;

    f32x4_t c0 = {0.f,0.f,0.f,0.f}, c1 = {0.f,0.f,0.f,0.f};
    c0 = __builtin_amdgcn_mfma_f32_16x16x32_f16(a0, *(const half8_t*)(wc0     ), c0, 0,0,0);
    c1 = __builtin_amdgcn_mfma_f32_16x16x32_f16(a0, *(const half8_t*)(wc1     ), c1, 0,0,0);
    c0 = __builtin_amdgcn_mfma_f32_16x16x32_f16(a1, *(const half8_t*)(wc0 + 32), c0, 0,0,0);
    c1 = __builtin_amdgcn_mfma_f32_16x16x32_f16(a1, *(const half8_t*)(wc1 + 32), c1, 0,0,0);
    c0 = __builtin_amdgcn_mfma_f32_16x16x32_f16(a2, *(const half8_t*)(wc0 + 64), c0, 0,0,0);
    c1 = __builtin_amdgcn_mfma_f32_16x16x32_f16(a2, *(const half8_t*)(wc1 + 64), c1, 0,0,0);
    c0 = __builtin_amdgcn_mfma_f32_16x16x32_f16(a3, *(const half8_t*)(wc0 + 96), c0, 0,0,0);
    c1 = __builtin_amdgcn_mfma_f32_16x16x32_f16(a3, *(const half8_t*)(wc1 + 96), c1, 0,0,0);

    #pragma unroll
    for (int rg = 0; rg < 4; ++rg){
        int onode = nb + kg * 4 + rg;
        if (onode < n){
            H4[(size_t)onode * 16 + r] = (_Float16)c0[rg];
            if (r == 0) als4[onode] = c1[rg];       // col 16
            else if (r == 1) ald4[onode] = c1[rg];  // col 17
        }
    }
}

// ---------------- aggregation (128 ch, 4 heads): round-12 form (unroll x2, in-loop) ----------------

__global__ __launch_bounds__(256) void aggregate128_kernel(const __half* __restrict__ H16,
                                                           const float* __restrict__ als,
                                                           const float* __restrict__ ald,
                                                           const int* __restrict__ cnt,
                                                           const unsigned short* __restrict__ csr,
                                                           const float* __restrict__ bias,
                                                           _Float16* __restrict__ out16,
                                                           int n){
    int node = blockIdx.x * 4 + (threadIdx.x >> 6);
    int lane = threadIdx.x & 63;
    if (node >= n) return;
    int start = node << 6;
    int deg = cnt[node];
    int end = start + deg;

    int eg = lane >> 4, cl = lane & 15;
    int h = cl >> 2;
    float ad_h = ald[(size_t)node * 4 + h];

    float den = 0.f;
    float acc[8] = {0,0,0,0,0,0,0,0};
    const __half* Hc = H16 + cl * 8;
    int i = start + eg;
    for (; i + 4 < end; i += 8){
        int sA = csr[i];
        int sB = csr[i + 4];
        float eA = als[(size_t)sA * 4 + h] + ad_h; eA = eA > 0.f ? eA : 0.2f * eA;
        float eB = als[(size_t)sB * 4 + h] + ad_h; eB = eB > 0.f ? eB : 0.2f * eB;
        float wA = __expf(eA);
        float wB = __expf(eB);
        den += wA + wB;
        uint4 ra = *(const uint4*)(Hc + (size_t)sA * 128);
        uint4 rb = *(const uint4*)(Hc + (size_t)sB * 128);
        float2 a0 = __half22float2(*(__half2*)&ra.x);
        float2 a1 = __half22float2(*(__half2*)&ra.y);
        float2 a2 = __half22float2(*(__half2*)&ra.z);
        float2 a3 = __half22float2(*(__half2*)&ra.w);
        float2 b0 = __half22float2(*(__half2*)&rb.x);
        float2 b1 = __half22float2(*(__half2*)&rb.y);
        float2 b2 = __half22float2(*(__half2*)&rb.z);
        float2 b3 = __half22float2(*(__half2*)&rb.w);
        acc[0] += wA * a0.x + wB * b0.x; acc[1] += wA * a0.y + wB * b0.y;
        acc[2] += wA * a1.x + wB * b1.x; acc[3] += wA * a1.y + wB * b1.y;
        acc[4] += wA * a2.x + wB * b2.x; acc[5] += wA * a2.y + wB * b2.y;
        acc[6] += wA * a3.x + wB * b3.x; acc[7] += wA * a3.y + wB * b3.y;
    }
    if (i < end){
        int s = csr[i];
        float e = als[(size_t)s * 4 + h] + ad_h; e = e > 0.f ? e : 0.2f * e;
        float w = __expf(e);
        den += w;
        uint4 ra = *(const uint4*)(Hc + (size_t)s * 128);
        float2 a0 = __half22float2(*(__half2*)&ra.x);
        float2 a1 = __half22float2(*(__half2*)&ra.y);
        float2 a2 = __half22float2(*(__half2*)&ra.z);
        float2 a3 = __half22float2(*(__half2*)&ra.w);
        acc[0] += w * a0.x; acc[1] += w * a0.y;
        acc[2] += w * a1.x; acc[3] += w * a1.y;
        acc[4] += w * a2.x; acc[5] += w * a2.y;
        acc[6] += w * a3.x; acc[7] += w * a3.y;
    }
    #pragma unroll
    for (int j = 0; j < 8; ++j){
        acc[j] += __shfl_xor(acc[j], 16);
        acc[j] += __shfl_xor(acc[j], 32);
    }
    den += __shfl_xor(den, 16);
    den += __shfl_xor(den, 32);

    if (eg == 0){
        float inv = 1.f / (den + 1e-16f);
        int col = cl * 8;
        float4 bv0 = *(const float4*)(bias + col);
        float4 bv1 = *(const float4*)(bias + col + 4);
        float v[8];
        v[0] = acc[0]*inv + bv0.x; v[1] = acc[1]*inv + bv0.y;
        v[2] = acc[2]*inv + bv0.z; v[3] = acc[3]*inv + bv0.w;
        v[4] = acc[4]*inv + bv1.x; v[5] = acc[5]*inv + bv1.y;
        v[6] = acc[6]*inv + bv1.z; v[7] = acc[7]*inv + bv1.w;
        #pragma unroll
        for (int j = 0; j < 8; ++j) v[j] = v[j] > 0.f ? v[j] : __expf(v[j]) - 1.f;  // ELU

        half8_t o16 = {(_Float16)v[0], (_Float16)v[1], (_Float16)v[2], (_Float16)v[3],
                       (_Float16)v[4], (_Float16)v[5], (_Float16)v[6], (_Float16)v[7]};
        *(half8_t*)&out16[(size_t)node * 128 + col] = o16;
    }
}

// ---------------- aggregation (16 ch, 1 head): fp16 gather, in-loop form ----------------

__global__ __launch_bounds__(256) void aggregate16_kernel(const _Float16* __restrict__ H4,
                                                          const float* __restrict__ als4,
                                                          const float* __restrict__ ald4,
                                                          const int* __restrict__ cnt,
                                                          const unsigned short* __restrict__ csr,
                                                          const float* __restrict__ bias,
                                                          float* __restrict__ out, int n){
    int node = blockIdx.x * 4 + (threadIdx.x >> 6);
    int lane = threadIdx.x & 63;
    if (node >= n) return;
    int start = node << 6, deg = cnt[node];
    float adn = ald4[node];

    int eg = lane >> 2, cl = lane & 3;
    float den = 0.f;
    float acc0 = 0.f, acc1 = 0.f, acc2 = 0.f, acc3 = 0.f;
    for (int i = eg; i < deg; i += 16){
        int s = csr[start + i];
        float e = als4[s] + adn; e = e > 0.f ? e : 0.2f * e;
        float w = __expf(e);
        den += w;
        uint2 hv = *(const uint2*)(H4 + (size_t)s * 16 + cl * 4);
        float2 h0 = __half22float2(*(__half2*)&hv.x);
        float2 h1 = __half22float2(*(__half2*)&hv.y);
        acc0 += w * h0.x; acc1 += w * h0.y; acc2 += w * h1.x; acc3 += w * h1.y;
    }
    #pragma unroll
    for (int off = 4; off <= 32; off <<= 1){
        acc0 += __shfl_xor(acc0, off); acc1 += __shfl_xor(acc1, off);
        acc2 += __shfl_xor(acc2, off); acc3 += __shfl_xor(acc3, off);
        den  += __shfl_xor(den,  off);
    }

    if (eg == 0){
        float inv = 1.f / (den + 1e-16f);
        float4 bv = *(const float4*)(bias + cl * 4);
        float4 o = {acc0*inv + bv.x, acc1*inv + bv.y, acc2*inv + bv.z, acc3*inv + bv.w};
        *(float4*)&out[(size_t)node * 16 + cl * 4] = o;
    }
}

// ---------------- launcher ----------------

extern "C" void kernel_launch(void* const* d_in, const int* in_sizes, int n_in,
                              void* d_out, int out_size, void* d_ws, size_t ws_size,
                              hipStream_t stream) {
    const float* x   = (const float*)d_in[0];
    const int*   ei  = (const int*)d_in[1];
    const float* W1  = (const float*)d_in[3];
    const float* as1 = (const float*)d_in[4];
    const float* ad1 = (const float*)d_in[5];
    const float* b1  = (const float*)d_in[6];
    const float* Wh  = (const float*)d_in[7];
    const float* ash = (const float*)d_in[8];
    const float* adh = (const float*)d_in[9];
    const float* bh  = (const float*)d_in[10];
    const float* W2  = (const float*)d_in[11];
    const float* as2 = (const float*)d_in[12];
    const float* ad2 = (const float*)d_in[13];
    const float* b2  = (const float*)d_in[14];

    int N = in_sizes[0] / 128;
    int E = in_sizes[1] / 2;
    int Et = E + N;
    const int* srcA = ei;
    const int* dstA = ei + E;

    char* ws = (char*)d_ws;
    size_t off = 0;
    auto alloc = [&](size_t bytes) -> void* {
        void* p = ws + off;
        off = (off + bytes + 255) & ~(size_t)255;
        return p;
    };
    int* cnt      = (int*)alloc((size_t)N * 4);
    unsigned short* csr = (unsigned short*)alloc((size_t)N * 64 * 2);
    _Float16* xbuf16 = (_Float16*)alloc((size_t)N * 128 * 2);
    _Float16* h16    = (_Float16*)alloc((size_t)N * 128 * 2);
    _Float16* wtx    = (_Float16*)alloc((size_t)3 * 144 * 128 * 2);
    _Float16* w2x    = (_Float16*)alloc((size_t)32 * 128 * 2);
    float* als_a  = (float*)alloc((size_t)N * 4 * 4);
    float* ald_a  = (float*)alloc((size_t)N * 4 * 4);
    _Float16* h4  = (_Float16*)alloc((size_t)N * 16 * 2);
    float* als4   = (float*)alloc((size_t)N * 4);
    float* ald4   = (float*)alloc((size_t)N * 4);

    zero_cnt_kernel<<<divup(divup(N, 4), 256), 256, 0, stream>>>(cnt, N);
    prep_kernel<<<divup(3 * 144 * 128 + 32 * 128, 256), 256, 0, stream>>>(
        W1, Wh, as1, ad1, ash, adh, W2, as2, ad2, wtx, w2x);
    fill_sliced_kernel<<<divup(Et, 256) * 8, 256, 0, stream>>>(srcA, dstA, cnt, csr, E, Et);

    float* out = (float*)d_out;
    const size_t WSTRIDE = (size_t)144 * 128;

    // layer 1 (fp32 input, converted in-register)
    gemm128L_f32_kernel<<<divup(N, 16), 256, 0, stream>>>(x, wtx, h16, als_a, ald_a, N);
    aggregate128_kernel<<<divup(N, 4), 256, 0, stream>>>((const __half*)h16, als_a, ald_a, cnt, csr,
                                                        b1, xbuf16, N);
    // layer 2
    gemm128L_f16_kernel<<<divup(N, 16), 256, 0, stream>>>(xbuf16, wtx + WSTRIDE, h16, als_a, ald_a, N);
    aggregate128_kernel<<<divup(N, 4), 256, 0, stream>>>((const __half*)h16, als_a, ald_a, cnt, csr,
                                                        bh, xbuf16, N);
    // layer 3
    gemm128L_f16_kernel<<<divup(N, 16), 256, 0, stream>>>(xbuf16, wtx + 2 * WSTRIDE, h16, als_a, ald_a, N);
    aggregate128_kernel<<<divup(N, 4), 256, 0, stream>>>((const __half*)h16, als_a, ald_a, cnt, csr,
                                                        bh + 128, xbuf16, N);

    // layer 4 (heads=1, 16 out): fused GEMM+logits, fp16 H4
    gemm16L_kernel<<<divup(N, 64), 256, 0, stream>>>(xbuf16, w2x, h4, als4, ald4, N);
    aggregate16_kernel<<<divup(N, 4), 256, 0, stream>>>(h4, als4, ald4, cnt, csr, b2, out, N);
}